// Round 4
// baseline (40.765 us; speedup 1.0000x reference)
//
#include <hip/hip_runtime.h>

// Problem: B=64, C=3, S=384, P=32, R=169
//   out0: patches (B*R, C, P, P) f32 -> 33,226,752 elems
//   out1: pos     (B, R, 2)      f32 -> 21,632 elems (flat after patches)
//
// out[b,r,c,i,j] = bilinear sample of x[b,c,·,·] at
//   row = (j + crop_left[b,r]) * scale   (j = output fast axis)
//   col = (i + crop_top [b,r]) * scale
// scale = 383/384 < 1. Verified R1-R3: 33x33 window at floor(crop*scale)
// suffices, always in-bounds, clamp never binds. absmax 0.016 vs thr 7.04.
//
// R4 vs R3 (39.85us): traffic model says we're at ~7.2 TB/s combined already
// (288 MB client / 40us). Lever: occupancy/latency — 256-thr blocks -> 8
// resident patches/CU (was 4) to decouple per-block barrier drains; j-quad
// per thread -> f4 nontemporal stores (wave = 1KB/instr).
#define Bn 64
#define Cn 3
#define Sn 384
#define Pn 32
#define Rn 169
#define TCOLS 36                       // 33 needed + <=3 alignment slack
#define TROWS 33
#define PLANE (TCOLS * TROWS)          // 1188
#define PATCH_ELEMS (Cn * Pn * Pn)     // 3072
#define POS_OFFSET ((size_t)Bn * Rn * Cn * Pn * Pn)  // 33226752
#define NBLK (Bn * Rn)                 // 10816 = 8 * 1352

typedef float f4 __attribute__((ext_vector_type(4)));

__global__ __launch_bounds__(256) void patch_kernel(
    const float* __restrict__ x,         // (B, C, S, S)
    const int*   __restrict__ crop_top,  // (B, R) -> column axis (i)
    const int*   __restrict__ crop_left, // (B, R) -> row axis (j)
    float*       __restrict__ out)
{
    // XCD-bijective swizzle: 10816 % 8 == 0; consecutive pr share one image
    // for 169 blocks -> image (1.77 MB) L2-resident per XCD.
    const int bid = blockIdx.x;
    const int pr  = (bid & 7) * (NBLK / 8) + (bid >> 3);
    const int b   = pr / Rn;
    const int t   = threadIdx.x;

    // Transposed tile: T[c][col][row] (row = j axis = fast axis).
    __shared__ float T[Cn * PLANE];      // 14256 B -> 8 blocks/CU fits 114KB

    const float scale = 383.0f / 384.0f;

    const int ct = crop_top[pr];         // block-uniform -> scalar regs
    const int cl = crop_left[pr];
    const float ctf = (float)ct;
    const float clf = (float)cl;
    const int col_base = (int)floorf(ctf * scale);
    const int row_base = (int)floorf(clf * scale);
    const int start    = col_base & ~3;  // 16B-aligned window start

    const float* xb = x + (size_t)b * (Cn * Sn * Sn);

    // ---- Stage: 99 rows x 9 aligned dwordx4 = 891 tasks over 256 thr ----
    #pragma unroll
    for (int k = 0; k < 4; ++k) {
        int idx = t + k * 256;
        if (idx < 99 * 9) {
            int row = idx / 9;                       // magic-mul
            int q4  = (idx - row * 9) << 2;          // col 0,4,...,32
            int c   = (row >= 66) ? 2 : ((row >= 33) ? 1 : 0);
            int rr  = row - c * 33;
            const f4 g = *(const f4*)(xb + c * (Sn * Sn)
                                         + (row_base + rr) * Sn + start + q4);
            int a = c * PLANE + q4 * TROWS + rr;     // transposed scatter
            T[a]             = g.x;                  // -> 2x ds_write2_b32
            T[a + TROWS]     = g.y;
            T[a + 2 * TROWS] = g.z;
            T[a + 3 * TROWS] = g.w;
        }
    }

    // pos[b,r,0] = crop_top, pos[b,r,1] = crop_left (before barrier, free slot)
    if (t < 2) {
        out[POS_OFFSET + (size_t)pr * 2 + t] = (t == 0) ? ctf : clf;
    }
    __syncthreads();

    // ---- Compute: thread owns (j-quad = 4*(t&7), i = t>>3) ----
    // Wave store footprint: 8 jq-lanes x 16B = full 128B j-line, 8 i-groups
    // -> 1KB contiguous per wave-store instruction.
    const int jq = (t & 7) << 2;         // 0,4,...,28
    const int i  = t >> 3;               // 0..31

    float cx = ((float)i + ctf) * scale;
    float fx = floorf(cx);
    float wx = cx - fx;
    int   x0 = (int)fx - start;          // in [0,34]; +1 <= 35 < TCOLS
    float owx = 1.0f - wx;

    float wyv[4], owyv[4];
    int   basev[4];
    #pragma unroll
    for (int jj = 0; jj < 4; ++jj) {
        float cy = ((float)(jq + jj) + clf) * scale;
        float fy = floorf(cy);
        float wy = cy - fy;
        int   y0 = (int)fy - row_base;   // in [0,31]
        wyv[jj]  = wy;
        owyv[jj] = 1.0f - wy;
        basev[jj] = x0 * TROWS + y0;
        // bank = (33*i + 4*jq + dy) % 32 -> exactly 2 lanes/bank (free, m136)
    }

    float* outp = out + (size_t)pr * PATCH_ELEMS + i * Pn + jq;

    #pragma unroll
    for (int c = 0; c < Cn; ++c) {
        const float* Tc = T + c * PLANE;
        f4 v;
        #pragma unroll
        for (int jj = 0; jj < 4; ++jj) {
            int base = basev[jj];
            float v00 = Tc[base];                // (y0,   x0)   } ds_read2
            float v10 = Tc[base + 1];            // (y0+1, x0)   }
            float v01 = Tc[base + TROWS];        // (y0,   x0+1) } ds_read2
            float v11 = Tc[base + TROWS + 1];    // (y0+1, x0+1) }
            float c0 = owyv[jj] * v00 + wyv[jj] * v10;   // col x0 lerp
            float c1 = owyv[jj] * v01 + wyv[jj] * v11;   // col x0+1 lerp
            v[jj] = owx * c0 + wx * c1;
        }
        __builtin_nontemporal_store(v, (f4*)(outp + c * (Pn * Pn)));
    }
}

extern "C" void kernel_launch(void* const* d_in, const int* in_sizes, int n_in,
                              void* d_out, int out_size, void* d_ws, size_t ws_size,
                              hipStream_t stream) {
    const float* x         = (const float*)d_in[0];
    const int*   crop_top  = (const int*)d_in[1];
    const int*   crop_left = (const int*)d_in[2];
    float*       out       = (float*)d_out;

    patch_kernel<<<dim3(NBLK), dim3(256), 0, stream>>>(x, crop_top, crop_left, out);
}